// Round 5
// baseline (153.241 us; speedup 1.0000x reference)
//
#include <hip/hip_runtime.h>
#include <hip/hip_bf16.h>
#include <stdint.h>

typedef __attribute__((ext_vector_type(8))) short short8;
typedef __attribute__((ext_vector_type(4))) short short4_t;
typedef __attribute__((ext_vector_type(4))) float f32x4;
typedef __attribute__((ext_vector_type(2))) unsigned int u32x2;
typedef __attribute__((ext_vector_type(4))) unsigned int u32x4;

union FragU { u32x4 u; short8 s; };
union Frag2U { u32x2 u; short4_t s; };

__device__ __forceinline__ unsigned short f2bf(float f) {
  union { float f; uint32_t u; } v; v.f = f;
  uint32_t u = v.u;
  return (unsigned short)((u + 0x7FFFu + ((u >> 16) & 1u)) >> 16);
}

__device__ __forceinline__ unsigned pk2(float a, float b) {
  return (unsigned)f2bf(a) | ((unsigned)f2bf(b) << 16);
}

__device__ __forceinline__ void gload_lds16(const void* g, void* l) {
  __builtin_amdgcn_global_load_lds(
      (const __attribute__((address_space(1))) unsigned int*)g,
      (__attribute__((address_space(3))) unsigned int*)l, 16, 0, 0);
}

#if defined(__has_builtin)
#if __has_builtin(__builtin_amdgcn_mfma_f32_16x16x16bf16_1k)
#define HAVE_MFMA16_BUILTIN 1
#endif
#endif

__device__ __forceinline__ f32x4 mfma16(u32x2 a, u32x2 b, f32x4 c) {
#ifdef HAVE_MFMA16_BUILTIN
  Frag2U ua, ub;
  ua.u = a; ub.u = b;
  return __builtin_amdgcn_mfma_f32_16x16x16bf16_1k(ua.s, ub.s, c, 0, 0, 0);
#else
  asm volatile("s_nop 1\n\t"
               "v_mfma_f32_16x16x16_bf16 %0, %1, %2, %0\n\t"
               "s_nop 7\n\t"
               "s_nop 7"
               : "+v"(c) : "v"(a), "v"(b));
  return c;
#endif
}

// ---------------- K0: convert W (f32, [n][k] row-major) -> bf16, same layout ----------------
__global__ __launch_bounds__(256) void k_wconv(const float* __restrict__ WQ,
                                               const float* __restrict__ WK,
                                               const float* __restrict__ WV,
                                               unsigned short* __restrict__ Wbf) {
  int mat = blockIdx.x >> 5;          // 0..2
  int i = blockIdx.x & 31;            // 32 blocks/mat
  const float* W = (mat == 0) ? WQ : ((mat == 1) ? WK : WV);
  int off = i * 2048 + threadIdx.x * 8;
  f32x4 v0 = *(const f32x4*)(W + off), v1 = *(const f32x4*)(W + off + 4);
  u32x4 pk;
  pk.x = pk2(v0.x, v0.y); pk.y = pk2(v0.z, v0.w);
  pk.z = pk2(v1.x, v1.y); pk.w = pk2(v1.z, v1.w);
  *(u32x4*)(Wbf + (size_t)mat * 65536 + off) = pk;
}

// ---------------- K1a: per-column partial sums over 64-row chunks ----------------
__global__ __launch_bounds__(256) void k_stats(const float* __restrict__ x,
                                               float* __restrict__ psum,
                                               float* __restrict__ psq) {
  int t = threadIdx.x;
  int cb = blockIdx.x & 3;
  int ck = blockIdx.x >> 2;
  int c0 = cb * 1024 + t * 4;
  f32x4 s = {0.f, 0.f, 0.f, 0.f}, q = {0.f, 0.f, 0.f, 0.f};
  const float* base = x + (size_t)ck * 64 * 4096 + c0;
#pragma unroll 4
  for (int r = 0; r < 64; ++r) {
    f32x4 v = *(const f32x4*)(base + (size_t)r * 4096);
    s += v;
    q += v * v;
  }
  *(f32x4*)(psum + (size_t)ck * 4096 + c0) = s;
  *(f32x4*)(psq + (size_t)ck * 4096 + c0) = q;
}

// ---------------- K1b: finalize BN -> fused scale/shift coeffs ----------------
__global__ __launch_bounds__(256) void k_finalize(const float* __restrict__ psum,
                                                  const float* __restrict__ psq,
                                                  const float* __restrict__ gamma,
                                                  const float* __restrict__ beta,
                                                  float* __restrict__ An,
                                                  float* __restrict__ Bn) {
  int c = blockIdx.x * 256 + threadIdx.x;
  float s = 0.f, q = 0.f;
  for (int k = 0; k < 64; ++k) {
    s += psum[k * 4096 + c];
    q += psq[k * 4096 + c];
  }
  float mean = s * (1.0f / 4096.0f);
  float var = q * (1.0f / 4096.0f) - mean * mean;
  float a = gamma[c] * rsqrtf(var + 1e-5f);
  An[c] = a;
  Bn[c] = beta[c] - mean * a;
}

// ---------------- K2: Xn[65536,256] @ W^T (+bias) -> Qt,Kt (transposed) and V ----------------
// M=64 tile, A in LDS (32 KB, swizzled). B-frags straight from global bf16 W (L2-resident).
__global__ __launch_bounds__(256) void k_qkv(
    const float* __restrict__ x, const float* __restrict__ An, const float* __restrict__ Bn,
    const unsigned short* __restrict__ Wbf,
    const float* __restrict__ bQ, const float* __restrict__ bK, const float* __restrict__ bV,
    unsigned short* __restrict__ Qt, unsigned short* __restrict__ Kt,
    unsigned short* __restrict__ Vo) {
  __shared__ unsigned short Asm[64 * 256];
  int t = threadIdx.x;
  int mb = blockIdx.x;

  // stage A (normalize + bf16): 8 iters x 8 rows
  for (int i = 0; i < 8; ++i) {
    int m = i * 8 + (t >> 5);
    int k0 = (t & 31) * 8;
    size_t r = (size_t)(mb * 64 + m);
    const float* xs = x + r * 256 + k0;
    f32x4 v0 = *(const f32x4*)(xs), v1 = *(const f32x4*)(xs + 4);
    int c = ((int)(r & 15)) * 256 + k0;
    f32x4 a0 = *(const f32x4*)(An + c), a1 = *(const f32x4*)(An + c + 4);
    f32x4 b0 = *(const f32x4*)(Bn + c), b1 = *(const f32x4*)(Bn + c + 4);
    f32x4 n0 = v0 * a0 + b0, n1 = v1 * a1 + b1;
    u32x4 pk;
    pk.x = pk2(n0.x, n0.y); pk.y = pk2(n0.z, n0.w);
    pk.z = pk2(n1.x, n1.y); pk.w = pk2(n1.z, n1.w);
    int off = m * 512 + ((k0 * 2) ^ ((m & 7) << 4));
    *(u32x4*)((char*)Asm + off) = pk;
  }
  __syncthreads();

  int w = t >> 6, ln = t & 63, lr = ln & 15, g = ln >> 4;
  int wn = w * 64;  // each wave: full M=64, N-quarter of 64

#pragma unroll
  for (int mat = 0; mat < 3; ++mat) {
    const unsigned short* W = Wbf + (size_t)mat * 65536;
    const float* bias = (mat == 0) ? bQ : ((mat == 1) ? bK : bV);
    float scale = (mat == 0) ? 0.0625f : 1.0f;

    f32x4 acc[4][4];
    f32x4 z4 = {0.f, 0.f, 0.f, 0.f};
#pragma unroll
    for (int a_ = 0; a_ < 4; ++a_)
#pragma unroll
      for (int b_ = 0; b_ < 4; ++b_) acc[a_][b_] = z4;

#pragma unroll
    for (int kk = 0; kk < 8; ++kk) {
      FragU af[4], bfr[4];
#pragma unroll
      for (int nt = 0; nt < 4; ++nt) {
        int n = wn + nt * 16 + lr;
        bfr[nt].u = *(const u32x4*)((const char*)W + (size_t)n * 512 + kk * 64 + g * 16);
      }
#pragma unroll
      for (int mt = 0; mt < 4; ++mt) {
        int m = mt * 16 + lr;
        af[mt].u = *(const u32x4*)((const char*)Asm + m * 512 + ((kk * 64 + g * 16) ^ ((m & 7) << 4)));
      }
#pragma unroll
      for (int mt = 0; mt < 4; ++mt)
#pragma unroll
        for (int nt = 0; nt < 4; ++nt)
          acc[mt][nt] = __builtin_amdgcn_mfma_f32_16x16x32_bf16(af[mt].s, bfr[nt].s, acc[mt][nt], 0, 0, 0);
    }

    // epilogue: C layout col=lane&15, row=(lane>>4)*4+reg
#pragma unroll
    for (int nt = 0; nt < 4; ++nt) {
      int ccol = wn + nt * 16 + lr;
      float bvs = bias[ccol] * scale;
#pragma unroll
      for (int mt = 0; mt < 4; ++mt) {
        int rbase = mb * 64 + mt * 16;
        int b_ = rbase >> 4;
#pragma unroll
        for (int rg = 0; rg < 4; ++rg) {
          int p_ = g * 4 + rg;
          unsigned short val = f2bf(acc[mt][nt][rg] * scale + bvs);
          if (mat < 2) {
            (mat == 0 ? Qt : Kt)[(size_t)b_ * 4096 + (size_t)ccol * 16 + p_] = val;
          } else {
            Vo[(size_t)(rbase + p_) * 256 + ccol] = val;
          }
        }
      }
    }
  }
}

// ---------------- K3: per-batch-row attention (plain layouts, 16x16x16 MFMAs) ----------------
#define LQT 0
#define LKT 8192
#define LVS 16384
#define LTOT 24576

__global__ __launch_bounds__(256, 3) void k_attn(
    const unsigned short* __restrict__ Qtg, const unsigned short* __restrict__ Ktg,
    const unsigned short* __restrict__ Vg, const float* __restrict__ x,
    float* __restrict__ out) {
  __shared__ char lds[LTOT];
  int b = blockIdx.x;
  int t = threadIdx.x;
  int w = t >> 6, ln = t & 63, lr = ln & 15, g = ln >> 4;

  // stage: Qt,Kt linear copy; V with involution swizzle on source
  for (int i = w; i < 24; i += 4) {
    const unsigned short* srcmat;
    unsigned srcbyte;
    int region;
    if (i < 8) {
      srcmat = Qtg;
      srcbyte = (unsigned)b * 8192 + i * 1024 + ln * 16;
      region = LQT + i * 1024;
    } else if (i < 16) {
      int ii = i - 8;
      srcmat = Ktg;
      srcbyte = (unsigned)b * 8192 + ii * 1024 + ln * 16;
      region = LKT + ii * 1024;
    } else {
      int ii = i - 16;
      srcmat = Vg;
      int d = ii * 1024 + ln * 16;
      int p = d >> 9;
      int cc = d & 511;
      srcbyte = (unsigned)b * 8192 + p * 512 + (unsigned)(cc ^ ((p & 7) << 4));
      region = LVS + ii * 1024;
    }
    gload_lds16((const char*)srcmat + srcbyte, &lds[region]);
  }
  __syncthreads();

  // Q B-frags (hoisted): B[k=p=g*4+j][n=e=lr]
  u32x2 qf[4];
#pragma unroll
  for (int nt = 0; nt < 4; ++nt)
    qf[nt] = *(const u32x2*)(&lds[LQT + (w * 64 + nt * 16 + lr) * 32 + g * 8]);

  f32x4 accT[4];
  float denp[4];
  f32x4 z4 = {0.f, 0.f, 0.f, 0.f};
#pragma unroll
  for (int nt = 0; nt < 4; ++nt) { accT[nt] = z4; denp[nt] = 0.f; }

  for (int c = 0; c < 8; ++c) {
#pragma unroll
    for (int mt_ = 0; mt_ < 2; ++mt_) {
      u32x2 kf = *(const u32x2*)(&lds[LKT + (c * 32 + mt_ * 16 + lr) * 32 + g * 8]);

      f32x4 st[4];
#pragma unroll
      for (int nt = 0; nt < 4; ++nt)
        st[nt] = mfma16(kf, qf[nt], z4);

      u32x2 vf = *(const u32x2*)(
          &lds[LVS + lr * 512 + ((c * 64 + mt_ * 32 + g * 8) ^ ((lr & 7) << 4))]);

#pragma unroll
      for (int nt = 0; nt < 4; ++nt) {
        float e0 = __expf(st[nt].x);
        float e1 = __expf(st[nt].y);
        float e2 = __expf(st[nt].z);
        float e3 = __expf(st[nt].w);
        denp[nt] += (e0 + e1) + (e2 + e3);
        u32x2 pB;
        pB.x = pk2(e0, e1);
        pB.y = pk2(e2, e3);
        accT[nt] = mfma16(vf, pB, accT[nt]);  // acc^T[p][e] += V^T . P
      }
    }
  }

  // den[e]: reduce partials across the 4 g-groups (e = lr is lane-local)
#pragma unroll
  for (int nt = 0; nt < 4; ++nt) {
    float v = denp[nt];
    v += __shfl_xor(v, 16);
    v += __shfl_xor(v, 32);
    denp[nt] = v;
  }

  // epilogue: lane holds acc^T[p=g*4+rg][e=w*64+nt*16+lr]
  size_t rowbase = (size_t)b * 4096;
#pragma unroll
  for (int nt = 0; nt < 4; ++nt) {
    int e = w * 64 + nt * 16 + lr;
    size_t col = (size_t)e * 16 + g * 4;
    float inv = 1.0f / denp[nt];
    f32x4 xr = *(const f32x4*)(x + rowbase + col);
    f32x4 o = accT[nt] * inv + xr;
    *(f32x4*)(out + rowbase + col) = o;
  }
}

extern "C" void kernel_launch(void* const* d_in, const int* in_sizes, int n_in,
                              void* d_out, int out_size, void* d_ws, size_t ws_size,
                              hipStream_t stream) {
  const float* x = (const float*)d_in[0];
  const float* WQ = (const float*)d_in[1];
  const float* bQ = (const float*)d_in[2];
  const float* WK = (const float*)d_in[3];
  const float* bK = (const float*)d_in[4];
  const float* WV = (const float*)d_in[5];
  const float* bV = (const float*)d_in[6];
  const float* gamma = (const float*)d_in[7];
  const float* beta = (const float*)d_in[8];
  float* out = (float*)d_out;
  char* ws = (char*)d_ws;

  float* psum = (float*)(ws);                                  // 1 MB
  float* psq = (float*)(ws + (1 << 20));                       // 1 MB
  float* An = (float*)(ws + (2 << 20));                        // 16 KB
  float* Bn = (float*)(ws + (2 << 20) + (16 << 10));           // 16 KB
  unsigned short* Wbf = (unsigned short*)(ws + (3 << 20));     // 384 KB
  unsigned short* Qt = (unsigned short*)(ws + (size_t)(4 << 20));                 // 32 MB [b][e][p]
  unsigned short* Kt = (unsigned short*)(ws + (size_t)(4 << 20) + (32u << 20));   // 32 MB [b][f][p]
  unsigned short* Vo = (unsigned short*)(ws + (size_t)(4 << 20) + (64u << 20));   // 32 MB [b*16+p][e]

  hipLaunchKernelGGL(k_wconv, dim3(96), dim3(256), 0, stream, WQ, WK, WV, Wbf);
  hipLaunchKernelGGL(k_stats, dim3(256), dim3(256), 0, stream, x, psum, psq);
  hipLaunchKernelGGL(k_finalize, dim3(16), dim3(256), 0, stream, psum, psq, gamma, beta, An, Bn);
  hipLaunchKernelGGL(k_qkv, dim3(1024), dim3(256), 0, stream, x, An, Bn,
                     Wbf, bQ, bK, bV, Qt, Kt, Vo);
  hipLaunchKernelGGL(k_attn, dim3(4096), dim3(256), 0, stream, Qt, Kt, Vo, x, out);
}